// Round 3
// baseline (1211.870 us; speedup 1.0000x reference)
//
#include <hip/hip_runtime.h>
#include <math.h>

#define LSEQ 1024
#define NB 16
#define NC 12
#define NH 256
#define NM 32
#define NS 3
#define NBLK 192
#define TWO_PI 6.283185307179586f

// ---- workspace layout (float offsets) ----
#define OFF_BAR   0          // 16 ints (memset each call)
#define OFF_MEANS 16         // 192
#define OFF_STDEV 208        // 192
#define OFF_EPART 400        // 96*256 = 24576
#define OFF_WT_RE 24976      // 24576
#define OFF_WT_IM 49552      // 24576
#define OFF_V     74128      // 3*256*1024 = 786432
#define OFF_PSQ0  860560     // 4*3*65536 = 786432
#define OFF_PSQ1  1646992    // 786432
#define OFF_H     2433424    // 1024
#define PSTR      196608     // partial-slice stride (3*256*256)

__device__ __forceinline__ void gbar(int* bar) {
  __syncthreads();
  if (threadIdx.x == 0) {
    int g = __hip_atomic_load(bar + 1, __ATOMIC_RELAXED, __HIP_MEMORY_SCOPE_AGENT);
    __threadfence();
    int a = __hip_atomic_fetch_add(bar, 1, __ATOMIC_ACQ_REL, __HIP_MEMORY_SCOPE_AGENT);
    if (a == NBLK - 1) {
      __hip_atomic_store(bar, 0, __ATOMIC_RELAXED, __HIP_MEMORY_SCOPE_AGENT);
      __hip_atomic_fetch_add(bar + 1, 1, __ATOMIC_RELEASE, __HIP_MEMORY_SCOPE_AGENT);
    } else {
      while (__hip_atomic_load(bar + 1, __ATOMIC_ACQUIRE, __HIP_MEMORY_SCOPE_AGENT) == g)
        __builtin_amdgcn_s_sleep(2);
    }
  }
  __syncthreads();
}

__device__ __forceinline__ float block_reduce_sum(float v, float* sbuf) {
  int t = threadIdx.x;
  sbuf[t] = v; __syncthreads();
  for (int off = 128; off > 0; off >>= 1) {
    if (t < off) sbuf[t] += sbuf[t + off];
    __syncthreads();
  }
  float r = sbuf[0];
  __syncthreads();
  return r;
}

#define FMA_ROW(r, av) { acc[r][0] += (av)*b4.x; acc[r][1] += (av)*b4.y; acc[r][2] += (av)*b4.z; acc[r][3] += (av)*b4.w; }

// 128x64 output tile, K-slice of 64 (2 chunks of 32). 256 threads, 8x4 acc/thread.
__device__ void gemm64(float* As, float* Bs,
                       const float* Abase, int anp,
                       const float* Bbase, int bnp, int bld, int colLimit,
                       int rowbase, int colbase, int kb0,
                       float* outp, int outld, int outcol0, int outColLim,
                       bool atomicOut) {
  const int tid = threadIdx.x;
  const int tx = tid & 15, ty = tid >> 4;
  const int kkA = tid & 31, rA = tid >> 5;
  const int jB = tid & 63, kB = tid >> 6;
  float acc[8][4];
  #pragma unroll
  for (int i = 0; i < 8; ++i)
    #pragma unroll
    for (int j = 0; j < 4; ++j) acc[i][j] = 0.f;

  for (int ch = 0; ch < 2; ++ch) {
    int kb = kb0 + ch * 32;
    #pragma unroll
    for (int p = 0; p < 16; ++p) {
      int row = rowbase + rA + 8 * p;
      float v = 0.f;
      for (int pp = 0; pp < anp; ++pp) v += Abase[pp * PSTR + row * 256 + kb + kkA];
      As[kkA * 132 + rA + 8 * p] = v;
    }
    #pragma unroll
    for (int q = 0; q < 8; ++q) {
      int kk = kB + 4 * q;
      int j = colbase + jB;
      float v = 0.f;
      if (j < colLimit) {
        for (int pp = 0; pp < bnp; ++pp) v += Bbase[pp * PSTR + (kb + kk) * bld + j];
      }
      Bs[kk * 68 + jB] = v;
    }
    __syncthreads();
    #pragma unroll
    for (int kk = 0; kk < 32; ++kk) {
      float4 b4 = *(const float4*)(Bs + kk * 68 + tx * 4);
      float4 a0 = *(const float4*)(As + kk * 132 + ty * 8);
      float4 a1 = *(const float4*)(As + kk * 132 + ty * 8 + 4);
      FMA_ROW(0, a0.x) FMA_ROW(1, a0.y) FMA_ROW(2, a0.z) FMA_ROW(3, a0.w)
      FMA_ROW(4, a1.x) FMA_ROW(5, a1.y) FMA_ROW(6, a1.z) FMA_ROW(7, a1.w)
    }
    __syncthreads();
  }
  if (!atomicOut) {
    #pragma unroll
    for (int i = 0; i < 8; ++i) {
      int row = rowbase + ty * 8 + i;
      float4 st; st.x = acc[i][0]; st.y = acc[i][1]; st.z = acc[i][2]; st.w = acc[i][3];
      *(float4*)(outp + (size_t)row * outld + outcol0 + colbase + tx * 4) = st;
    }
  } else {
    #pragma unroll
    for (int i = 0; i < 8; ++i) {
      int row = rowbase + ty * 8 + i;
      #pragma unroll
      for (int j = 0; j < 4; ++j) {
        int c = colbase + tx * 4 + j;
        if (c < outColLim) atomicAdd(outp + (size_t)row * outld + outcol0 + c, acc[i][j]);
      }
    }
  }
}

__device__ void wtilde_task(int w, float* smem, const float* wre, const float* wim,
                            const float* epart, float* wt_re, float* wt_im) {
  int s = w >> 8, i = w & 255;
  int t = threadIdx.x;
  float* ebs = smem;
  float* sr = smem + 256;
  float* si2 = smem + 512;
  float eb = 0.f;
  for (int chk = 0; chk < 32; ++chk) eb += epart[(s * 32 + chk) * 256 + t];
  ebs[t] = eb * (1.0f / LSEQ);
  __syncthreads();
  const float* br = wre + (size_t)(s * NH + i) * NH * NM;
  const float* bi = wim + (size_t)(s * NH + i) * NH * NM;
  float accR = 0.f, accI = 0.f;
  int g = t >> 5;
  for (int it = 0; it < 32; ++it) {
    int o = g + 8 * it;
    float e = ebs[o];
    int idx = t + 256 * it;
    accR += e * br[idx];
    accI += e * bi[idx];
  }
  sr[t] = accR; si2[t] = accI;
  __syncthreads();
  if (t < 32) {
    float aR = 0.f, aI = 0.f;
    for (int gg = 0; gg < 8; ++gg) { aR += sr[gg * 32 + t]; aI += si2[gg * 32 + t]; }
    wt_re[(size_t)(s * NM + t) * NH + i] = aR;
    wt_im[(size_t)(s * NM + t) * NH + i] = aI;
  }
  __syncthreads();
}

__global__ __launch_bounds__(256) void mega(const float* __restrict__ x,
    const float* __restrict__ aw, const float* __restrict__ ab,
    const float* __restrict__ wre, const float* __restrict__ wim,
    const float* __restrict__ w_mlp, const float* __restrict__ b_mlp,
    const float* __restrict__ w_fc, const float* __restrict__ b_fc,
    const float* __restrict__ A_mats, const float* __restrict__ Bv,
    const float* __restrict__ ev, float* __restrict__ ws, float* __restrict__ out) {
  __shared__ float smem[6608];
  int* bar = (int*)ws;
  float* means = ws + OFF_MEANS;
  float* stdev = ws + OFF_STDEV;
  float* epart = ws + OFF_EPART;
  float* wt_re = ws + OFF_WT_RE;
  float* wt_im = ws + OFF_WT_IM;
  float* V     = ws + OFF_V;
  float* PSQ0  = ws + OFF_PSQ0;
  float* PSQ1  = ws + OFF_PSQ1;
  float* H     = ws + OFF_H;
  const int blk = blockIdx.x;
  const int t = threadIdx.x;

  // ================= P0: stats | epart | V init | H/out init =================
  for (int task = blk; task < 1057; task += NBLK) {
    if (task < 192) {
      int b = task / NC, c = task % NC;
      float* xs = smem;
      float* red = smem + 1024;
      for (int e = 0; e < 4; ++e) {
        int tau = t + 256 * e;
        xs[tau] = x[((size_t)b * LSEQ + tau) * NC + c];
      }
      __syncthreads();
      float p = 0.f;
      for (int e = 0; e < 4; ++e) p += xs[t + 256 * e];
      float sum = block_reduce_sum(p, red);
      float mean = sum * (1.0f / LSEQ);
      float q = 0.f;
      for (int e = 0; e < 4; ++e) { float d = xs[t + 256 * e] - mean; q += d * d; }
      float sq = block_reduce_sum(q, red);
      if (t == 0) {
        means[task] = mean;
        stdev[task] = sqrtf(sq * (1.0f / LSEQ) + 1e-5f);
      }
      __syncthreads();
    } else if (task < 288) {
      int bb = task - 192;
      int s = bb >> 5, chk = bb & 31;
      float acc = 0.f;
      const float* base = ev + (size_t)s * LSEQ * NH + (size_t)chk * 32 * NH + t;
      for (int l = 0; l < 32; ++l) acc += base[(size_t)l * NH];
      epart[(size_t)bb * NH + t] = acc;
    } else if (task < 1056) {
      int row = task - 288;   // s*256 + i
      float* vr = V + (size_t)row * LSEQ;
      for (int j = t; j < 1024; j += 256) vr[j] = (j == 0) ? Bv[row] : 0.0f;
    } else {
      for (int e = 0; e < 4; ++e) H[t + 256 * e] = 0.0f;
      if (t < NB * 5) out[t] = b_fc[t % 5];
    }
  }
  gbar(bar);

  // ================= Chain: 10 stages (squares split-K exact, extends split-K atomic) ====
  const float* Pc = A_mats; int np = 1;
  float* Pn = PSQ0;
  float* As = smem;            // [32][132]
  float* Bs = smem + 4224;     // [32][68]
  for (int si = 0; si < 10; ++si) {
    const int m = 1 << si;
    const bool doSq = (si < 9);
    const int ntct = (m + 63) >> 6;
    const int nExt = 24 * ntct;
    const int estart = doSq ? 96 : 0;
    if (doSq && blk < 96) {
      int slice = blk & 3, rest = blk >> 2;
      int t8 = rest & 7, s = rest >> 3;
      int rt = t8 & 1, ct = t8 >> 1;
      const float* Ab = Pc + s * 65536;
      gemm64(As, Bs, Ab, np, Ab, np, 256, 256,
             rt * 128, ct * 64, slice * 64,
             Pn + slice * PSTR + s * 65536, 256, 0, 256, false);
    } else if (blk >= estart && blk - estart < nExt) {
      int e = blk - estart;
      int slice = e & 3, rt = (e >> 2) & 1, rest2 = e >> 3;
      int ct = rest2 % ntct, s = rest2 / ntct;
      gemm64(As, Bs, Pc + s * 65536, np, V + (size_t)s * 262144, 1, 1024, m,
             rt * 128, ct * 64, slice * 64,
             V + (size_t)s * 262144, 1024, m, m, true);
    } else if (si < 5 && blk >= 120) {
      int start = si * 154;
      int end = start + 154; if (end > 768) end = 768;
      for (int w = start + (blk - 120); w < end; w += 72)
        wtilde_task(w, smem, wre, wim, epart, wt_re, wt_im);
    }
    gbar(bar);
    if (doSq) { Pc = Pn; np = 4; Pn = (Pn == PSQ0) ? PSQ1 : PSQ0; }
  }

  // ================= utscan: 96 tasks =================
  if (blk < NS * NM) {
    int s = blk >> 5, k = blk & 31;
    float* sr = smem;
    float* si2 = smem + 1024;
    float* cr = smem + 2048;
    float* ci = smem + 2304;
    const float* wr = wt_re + (size_t)blk * NH;
    const float* wi_ = wt_im + (size_t)blk * NH;
    const float* Vs = V + (size_t)s * NH * LSEQ;
    float ar[4] = {0.f, 0.f, 0.f, 0.f}, ai[4] = {0.f, 0.f, 0.f, 0.f};
    for (int i = 0; i < NH; ++i) {
      float a = wr[i], b = wi_[i];
      const float* vrow = Vs + (size_t)i * LSEQ + t;
      #pragma unroll
      for (int e = 0; e < 4; ++e) {
        float v = vrow[256 * e];
        ar[e] += a * v; ai[e] += b * v;
      }
    }
    for (int e = 0; e < 4; ++e) {
      int d = t + 256 * e;
      int frac = (k * d) & 1023;
      float ang = -(TWO_PI / 1024.0f) * (float)frac;
      float sn, csn; sincosf(ang, &sn, &csn);
      sr[d] = ar[e] * csn - ai[e] * sn;
      si2[d] = ar[e] * sn + ai[e] * csn;
    }
    __syncthreads();
    float lr[4], li[4], rr = 0.f, ii = 0.f;
    for (int e = 0; e < 4; ++e) {
      rr += sr[4 * t + e]; ii += si2[4 * t + e];
      lr[e] = rr; li[e] = ii;
    }
    cr[t] = rr; ci[t] = ii;
    __syncthreads();
    for (int off = 1; off < 256; off <<= 1) {
      float pr = 0.f, pi = 0.f;
      if (t >= off) { pr = cr[t - off]; pi = ci[t - off]; }
      __syncthreads();
      cr[t] += pr; ci[t] += pi;
      __syncthreads();
    }
    float offr = (t > 0) ? cr[t - 1] : 0.0f;
    float offi = (t > 0) ? ci[t - 1] : 0.0f;
    for (int e = 0; e < 4; ++e) {
      sr[4 * t + e] = lr[e] + offr;
      si2[4 * t + e] = li[e] + offi;
    }
    __syncthreads();
    float wm = w_mlp[s];
    float coef = wm * ((k == 0) ? 1.0f : 2.0f) * (1.0f / LSEQ);
    for (int e = 0; e < 4; ++e) {
      int tau = t + 256 * e;
      int mIdx = 1023 - tau;
      int frac = (k * (tau + 1)) & 1023;
      float ang = -(TWO_PI / 1024.0f) * (float)frac;
      float sn, csn; sincosf(ang, &sn, &csn);
      float val = coef * (sr[mIdx] * csn - si2[mIdx] * sn);
      atomicAdd(&H[tau], val);
    }
  }
  gbar(bar);

  // ================= feat + out =================
  {
    int bc = blk;  // 192 tasks
    int b = bc / NC, c = bc % NC;
    float* red = smem;
    float mn = means[bc], sd = stdev[bc];
    float w = aw[c], bb = ab[c];
    float acc = 0.f;
    for (int e = 0; e < 4; ++e) {
      int tau = t + 256 * e;
      float xv = x[((size_t)b * LSEQ + tau) * NC + c];
      float f = (xv - mn) / sd * w + bb;
      acc += f * H[tau];
    }
    float sum = block_reduce_sum(acc, red);
    if (t == 0) {
      float mr = sum + b_mlp[0];
      float featv = (mr - bb) / (w + 1e-10f) * sd + mn;
      #pragma unroll
      for (int d = 0; d < 5; ++d)
        atomicAdd(&out[b * 5 + d], featv * w_fc[d * NC + c]);
    }
  }
}

extern "C" void kernel_launch(void* const* d_in, const int* in_sizes, int n_in,
                              void* d_out, int out_size, void* d_ws, size_t ws_size,
                              hipStream_t stream) {
  const float* x_enc   = (const float*)d_in[0];
  const float* aw      = (const float*)d_in[1];
  const float* ab      = (const float*)d_in[2];
  const float* wre     = (const float*)d_in[3];
  const float* wim     = (const float*)d_in[4];
  const float* w_mlp   = (const float*)d_in[5];
  const float* b_mlp   = (const float*)d_in[6];
  const float* w_fc    = (const float*)d_in[7];
  const float* b_fc    = (const float*)d_in[8];
  const float* A_mats  = (const float*)d_in[9];
  const float* B_vecs  = (const float*)d_in[10];
  const float* ev      = (const float*)d_in[11];

  hipMemsetAsync(d_ws, 0, 64, stream);  // barrier counters
  mega<<<NBLK, 256, 0, stream>>>(x_enc, aw, ab, wre, wim, w_mlp, b_mlp,
                                 w_fc, b_fc, A_mats, B_vecs, ev,
                                 (float*)d_ws, (float*)d_out);
}

// Round 4
// 530.894 us; speedup vs baseline: 2.2827x; 2.2827x over previous
//
#include <hip/hip_runtime.h>
#include <math.h>

#define LSEQ 1024
#define NB 16
#define NC 12
#define NH 256
#define NM 32
#define NS 3
#define TWO_PI 6.283185307179586f

// ---- workspace layout (float offsets) ----
#define OFF_MEANS 0          // 192
#define OFF_STDEV 192        // 192
#define OFF_EPART 384        // 96*256 = 24576
#define OFF_WT_RE 24960      // 24576
#define OFF_WT_IM 49536      // 24576
#define OFF_V     74112      // 3*256*1024 = 786432
#define OFF_PSQ0  860544     // 4*3*65536 = 786432
#define OFF_PSQ1  1646976    // 786432
#define OFF_H     2433408    // 1024
#define PSTR      196608     // partial-slice stride (3*256*256)

__device__ __forceinline__ float block_reduce_sum(float v, float* sbuf) {
  int t = threadIdx.x;
  sbuf[t] = v; __syncthreads();
  for (int off = 128; off > 0; off >>= 1) {
    if (t < off) sbuf[t] += sbuf[t + off];
    __syncthreads();
  }
  float r = sbuf[0];
  __syncthreads();
  return r;
}

// fused front: stats (0..191) | epart (192..287) | V zero+init (288..1055) | H/out init (1056)
__global__ __launch_bounds__(256) void k_front(const float* __restrict__ x,
                                               const float* __restrict__ Bv,
                                               const float* __restrict__ ev,
                                               const float* __restrict__ b_fc,
                                               float* __restrict__ means,
                                               float* __restrict__ stdev,
                                               float* __restrict__ epart,
                                               float* __restrict__ V,
                                               float* __restrict__ H,
                                               float* __restrict__ out) {
  __shared__ float smem[1280];
  int blk = blockIdx.x;
  int t = threadIdx.x;
  if (blk < 192) {
    int b = blk / NC, c = blk % NC;
    float* xs = smem;
    float* red = smem + 1024;
    for (int e = 0; e < 4; ++e) {
      int tau = t + 256 * e;
      xs[tau] = x[((size_t)b * LSEQ + tau) * NC + c];
    }
    __syncthreads();
    float p = 0.f;
    for (int e = 0; e < 4; ++e) p += xs[t + 256 * e];
    float sum = block_reduce_sum(p, red);
    float mean = sum * (1.0f / LSEQ);
    float q = 0.f;
    for (int e = 0; e < 4; ++e) { float d = xs[t + 256 * e] - mean; q += d * d; }
    float sq = block_reduce_sum(q, red);
    if (t == 0) {
      means[blk] = mean;
      stdev[blk] = sqrtf(sq * (1.0f / LSEQ) + 1e-5f);
    }
  } else if (blk < 288) {
    int bb = blk - 192;          // s*32 + chunk
    int s = bb >> 5, ch = bb & 31;
    float acc = 0.f;
    const float* base = ev + (size_t)s * LSEQ * NH + (size_t)ch * 32 * NH + t;
    for (int l = 0; l < 32; ++l) acc += base[(size_t)l * NH];
    epart[(size_t)bb * NH + t] = acc;
  } else if (blk < 1056) {
    int row = blk - 288;         // s*256 + i
    float* vr = V + (size_t)row * LSEQ;
    for (int j = t; j < 1024; j += 256) vr[j] = (j == 0) ? Bv[row] : 0.0f;
  } else {
    for (int e = 0; e < 4; ++e) H[t + 256 * e] = 0.0f;
    if (t < NB * 5) out[t] = b_fc[t % 5];
  }
}

#define FMA_ROW(r, av) { acc[r][0] += (av)*b4.x; acc[r][1] += (av)*b4.y; acc[r][2] += (av)*b4.z; acc[r][3] += (av)*b4.w; }

// 128x64 output tile, K-slice of 64 (2 chunks of 32). 256 threads, 8x4 acc/thread.
// Inputs may be carried as `np` partial slices (stride PSTR) summed during staging.
__device__ void gemm64(float* As, float* Bs,
                       const float* Abase, int anp,
                       const float* Bbase, int bnp, int bld, int colLimit,
                       int rowbase, int colbase, int kb0,
                       float* outp, int outld, int outcol0, int outColLim,
                       bool atomicOut) {
  const int tid = threadIdx.x;
  const int tx = tid & 15, ty = tid >> 4;
  const int kkA = tid & 31, rA = tid >> 5;
  const int jB = tid & 63, kB = tid >> 6;
  float acc[8][4];
  #pragma unroll
  for (int i = 0; i < 8; ++i)
    #pragma unroll
    for (int j = 0; j < 4; ++j) acc[i][j] = 0.f;

  for (int ch = 0; ch < 2; ++ch) {
    int kb = kb0 + ch * 32;
    #pragma unroll
    for (int p = 0; p < 16; ++p) {
      int row = rowbase + rA + 8 * p;
      float v = 0.f;
      for (int pp = 0; pp < anp; ++pp) v += Abase[pp * PSTR + row * 256 + kb + kkA];
      As[kkA * 132 + rA + 8 * p] = v;
    }
    #pragma unroll
    for (int q = 0; q < 8; ++q) {
      int kk = kB + 4 * q;
      int j = colbase + jB;
      float v = 0.f;
      if (j < colLimit) {
        for (int pp = 0; pp < bnp; ++pp) v += Bbase[pp * PSTR + (kb + kk) * bld + j];
      }
      Bs[kk * 68 + jB] = v;
    }
    __syncthreads();
    #pragma unroll
    for (int kk = 0; kk < 32; ++kk) {
      float4 b4 = *(const float4*)(Bs + kk * 68 + tx * 4);
      float4 a0 = *(const float4*)(As + kk * 132 + ty * 8);
      float4 a1 = *(const float4*)(As + kk * 132 + ty * 8 + 4);
      FMA_ROW(0, a0.x) FMA_ROW(1, a0.y) FMA_ROW(2, a0.z) FMA_ROW(3, a0.w)
      FMA_ROW(4, a1.x) FMA_ROW(5, a1.y) FMA_ROW(6, a1.z) FMA_ROW(7, a1.w)
    }
    __syncthreads();
  }
  if (!atomicOut) {
    #pragma unroll
    for (int i = 0; i < 8; ++i) {
      int row = rowbase + ty * 8 + i;
      float4 st; st.x = acc[i][0]; st.y = acc[i][1]; st.z = acc[i][2]; st.w = acc[i][3];
      *(float4*)(outp + (size_t)row * outld + outcol0 + colbase + tx * 4) = st;
    }
  } else {
    #pragma unroll
    for (int i = 0; i < 8; ++i) {
      int row = rowbase + ty * 8 + i;
      #pragma unroll
      for (int j = 0; j < 4; ++j) {
        int c = colbase + tx * 4 + j;
        if (c < outColLim) atomicAdd(outp + (size_t)row * outld + outcol0 + c, acc[i][j]);
      }
    }
  }
}

__device__ void wtilde_task(int w, float* smem, const float* wre, const float* wim,
                            const float* epart, float* wt_re, float* wt_im) {
  int s = w >> 8, i = w & 255;
  int t = threadIdx.x;
  float* ebs = smem;
  float* sr = smem + 256;
  float* si2 = smem + 512;
  float eb = 0.f;
  for (int chk = 0; chk < 32; ++chk) eb += epart[(s * 32 + chk) * 256 + t];
  ebs[t] = eb * (1.0f / LSEQ);
  __syncthreads();
  const float* br = wre + (size_t)(s * NH + i) * NH * NM;
  const float* bi = wim + (size_t)(s * NH + i) * NH * NM;
  float accR = 0.f, accI = 0.f;
  int g = t >> 5;
  for (int it = 0; it < 32; ++it) {
    int o = g + 8 * it;
    float e = ebs[o];
    int idx = t + 256 * it;   // == o*32 + k, coalesced
    accR += e * br[idx];
    accI += e * bi[idx];
  }
  sr[t] = accR; si2[t] = accI;
  __syncthreads();
  if (t < 32) {
    float aR = 0.f, aI = 0.f;
    for (int gg = 0; gg < 8; ++gg) { aR += sr[gg * 32 + t]; aI += si2[gg * 32 + t]; }
    wt_re[(size_t)(s * NM + t) * NH + i] = aR;
    wt_im[(size_t)(s * NM + t) * NH + i] = aI;
  }
  __syncthreads();
}

// one chain stage: squares (split-K4, partial slices) | extends (split-K4, atomic) | wtilde filler
__global__ __launch_bounds__(256) void k_chain(const float* __restrict__ Pc,
                                               float* __restrict__ Pn,
                                               float* __restrict__ V,
                                               const float* __restrict__ wre,
                                               const float* __restrict__ wim,
                                               const float* __restrict__ epart,
                                               float* __restrict__ wt_re,
                                               float* __restrict__ wt_im,
                                               int m, int np, int nSq, int ntct,
                                               int wstart) {
  __shared__ float smem[6608];
  float* As = smem;            // [32][132]
  float* Bs = smem + 4224;     // [32][68]
  const int blk = blockIdx.x;
  const int nExt = 24 * ntct;
  if (blk < nSq) {
    int slice = blk & 3, rest = blk >> 2;
    int t8 = rest & 7, s = rest >> 3;
    int rt = t8 & 1, ct = t8 >> 1;
    const float* Ab = Pc + s * 65536;
    gemm64(As, Bs, Ab, np, Ab, np, 256, 256,
           rt * 128, ct * 64, slice * 64,
           Pn + slice * PSTR + s * 65536, 256, 0, 256, false);
  } else if (blk < nSq + nExt) {
    int e = blk - nSq;
    int slice = e & 3, rt = (e >> 2) & 1, rest2 = e >> 3;
    int ct = rest2 % ntct, s = rest2 / ntct;
    gemm64(As, Bs, Pc + s * 65536, np, V + (size_t)s * 262144, 1, 1024, m,
           rt * 128, ct * 64, slice * 64,
           V + (size_t)s * 262144, 1024, m, m, true);
  } else {
    int w = wstart + (blk - nSq - nExt);
    if (w < NS * NH) wtilde_task(w, smem, wre, wim, epart, wt_re, wt_im);
  }
}

// fused: ut row (s,k) -> twiddle -> in-LDS prefix scan -> atomic H contribution
__global__ __launch_bounds__(256) void k_utscan(const float* __restrict__ wt_re,
                                                const float* __restrict__ wt_im,
                                                const float* __restrict__ V,
                                                const float* __restrict__ w_mlp,
                                                float* __restrict__ H) {
  int blk = blockIdx.x;   // s*NM + k
  int s = blk / NM, k = blk & 31;
  int t = threadIdx.x;
  __shared__ float sr[LSEQ], si_[LSEQ];
  __shared__ float cr[256], ci[256];
  const float* wr = wt_re + (size_t)blk * NH;
  const float* wi_ = wt_im + (size_t)blk * NH;
  const float* Vs = V + (size_t)s * NH * LSEQ;
  float ar[4] = {0.f, 0.f, 0.f, 0.f}, ai[4] = {0.f, 0.f, 0.f, 0.f};
  for (int i = 0; i < NH; ++i) {
    float a = wr[i], b = wi_[i];
    const float* vrow = Vs + (size_t)i * LSEQ + t;
    #pragma unroll
    for (int e = 0; e < 4; ++e) {
      float v = vrow[256 * e];
      ar[e] += a * v; ai[e] += b * v;
    }
  }
  for (int e = 0; e < 4; ++e) {
    int d = t + 256 * e;
    int frac = (k * d) & 1023;
    float ang = -(TWO_PI / 1024.0f) * (float)frac;
    float sn, csn; sincosf(ang, &sn, &csn);
    sr[d] = ar[e] * csn - ai[e] * sn;
    si_[d] = ar[e] * sn + ai[e] * csn;
  }
  __syncthreads();
  float lr[4], li[4], rr = 0.f, ii = 0.f;
  for (int e = 0; e < 4; ++e) {
    rr += sr[4 * t + e]; ii += si_[4 * t + e];
    lr[e] = rr; li[e] = ii;
  }
  cr[t] = rr; ci[t] = ii;
  __syncthreads();
  for (int off = 1; off < 256; off <<= 1) {
    float pr = 0.f, pi = 0.f;
    if (t >= off) { pr = cr[t - off]; pi = ci[t - off]; }
    __syncthreads();
    cr[t] += pr; ci[t] += pi;
    __syncthreads();
  }
  float offr = (t > 0) ? cr[t - 1] : 0.0f;
  float offi = (t > 0) ? ci[t - 1] : 0.0f;
  for (int e = 0; e < 4; ++e) {
    sr[4 * t + e] = lr[e] + offr;
    si_[4 * t + e] = li[e] + offi;
  }
  __syncthreads();
  float wm = w_mlp[s];
  float coef = wm * ((k == 0) ? 1.0f : 2.0f) * (1.0f / LSEQ);
  for (int e = 0; e < 4; ++e) {
    int tau = t + 256 * e;
    int mIdx = 1023 - tau;
    int frac = (k * (tau + 1)) & 1023;
    float ang = -(TWO_PI / 1024.0f) * (float)frac;
    float sn, csn; sincosf(ang, &sn, &csn);
    float val = coef * (sr[mIdx] * csn - si_[mIdx] * sn);
    atomicAdd(&H[tau], val);
  }
}

// feat per (b,c) + atomic accumulate into out (pre-initialized to b_fc)
__global__ __launch_bounds__(256) void k_feat(const float* __restrict__ x,
                                              const float* __restrict__ means,
                                              const float* __restrict__ stdev,
                                              const float* __restrict__ aw,
                                              const float* __restrict__ ab,
                                              const float* __restrict__ b_mlp,
                                              const float* __restrict__ H,
                                              const float* __restrict__ w_fc,
                                              float* __restrict__ out) {
  int bc = blockIdx.x; int b = bc / NC, c = bc % NC;
  __shared__ float red[256];
  int t = threadIdx.x;
  float mn = means[bc], sd = stdev[bc];
  float w = aw[c], bb = ab[c];
  float acc = 0.f;
  for (int e = 0; e < 4; ++e) {
    int tau = t + 256 * e;
    float xv = x[((size_t)b * LSEQ + tau) * NC + c];
    float f = (xv - mn) / sd * w + bb;
    acc += f * H[tau];
  }
  float sum = block_reduce_sum(acc, red);
  if (t == 0) {
    float mr = sum + b_mlp[0];
    float featv = (mr - bb) / (w + 1e-10f) * sd + mn;
    #pragma unroll
    for (int d = 0; d < 5; ++d)
      atomicAdd(&out[b * 5 + d], featv * w_fc[d * NC + c]);
  }
}

extern "C" void kernel_launch(void* const* d_in, const int* in_sizes, int n_in,
                              void* d_out, int out_size, void* d_ws, size_t ws_size,
                              hipStream_t stream) {
  const float* x_enc   = (const float*)d_in[0];
  const float* aw      = (const float*)d_in[1];
  const float* ab      = (const float*)d_in[2];
  const float* wre     = (const float*)d_in[3];
  const float* wim     = (const float*)d_in[4];
  const float* w_mlp   = (const float*)d_in[5];
  const float* b_mlp   = (const float*)d_in[6];
  const float* w_fc    = (const float*)d_in[7];
  const float* b_fc    = (const float*)d_in[8];
  const float* A_mats  = (const float*)d_in[9];
  const float* B_vecs  = (const float*)d_in[10];
  const float* ev      = (const float*)d_in[11];

  float* ws    = (float*)d_ws;
  float* means = ws + OFF_MEANS;
  float* stdev = ws + OFF_STDEV;
  float* epart = ws + OFF_EPART;
  float* wt_re = ws + OFF_WT_RE;
  float* wt_im = ws + OFF_WT_IM;
  float* V     = ws + OFF_V;
  float* PSQ0  = ws + OFF_PSQ0;
  float* PSQ1  = ws + OFF_PSQ1;
  float* H     = ws + OFF_H;
  float* out   = (float*)d_out;

  k_front<<<1057, 256, 0, stream>>>(x_enc, B_vecs, ev, b_fc, means, stdev, epart, V, H, out);

  const float* Pc = A_mats; int np = 1;
  float* Pn = PSQ0;
  for (int si = 0; si < 10; ++si) {
    int m = 1 << si;
    int doSq = (si < 9);
    int nSq = doSq ? 96 : 0;
    int ntct = (m + 63) >> 6;
    int nFill = (si < 5) ? 154 : 0;
    int grid = nSq + 24 * ntct + nFill;
    k_chain<<<grid, 256, 0, stream>>>(Pc, Pn, V, wre, wim, epart, wt_re, wt_im,
                                      m, np, nSq, ntct, si * 154);
    if (doSq) { Pc = Pn; np = 4; Pn = (Pn == PSQ0) ? PSQ1 : PSQ0; }
  }

  k_utscan<<<NS * NM, 256, 0, stream>>>(wt_re, wt_im, V, w_mlp, H);
  k_feat<<<192, 256, 0, stream>>>(x_enc, means, stdev, aw, ab, b_mlp, H, w_fc, out);
}